// Round 1
// baseline (144.958 us; speedup 1.0000x reference)
//
#include <hip/hip_runtime.h>
#include <hip/hip_bf16.h>
#include <stdint.h>

#define BB 8
#define CC 256
#define NN 4096
#define KK 16

typedef float f32x4 __attribute__((ext_vector_type(4)));
typedef short bf16x8 __attribute__((ext_vector_type(8)));

__device__ __forceinline__ ushort f2bf(float f) {
  union { float f; uint32_t u; } v; v.f = f;
  uint32_t r = v.u + 0x7FFFu + ((v.u >> 16) & 1u);   // RNE
  return (ushort)(r >> 16);
}
__device__ __forceinline__ float bf2f(ushort h) {
  union { uint32_t u; float f; } v; v.u = ((uint32_t)h) << 16;
  return v.f;
}

// K0: x[b][c][n] f32 -> xT[b][n][c] bf16  (64x64 LDS tile transpose)
__global__ __launch_bounds__(256) void k_transpose(
    const float* __restrict__ x, ushort* __restrict__ xT)
{
  __shared__ float tile[64][68];           // pad to 68 floats: f4-store aligned
  const int b  = blockIdx.z;
  const int c0 = blockIdx.y * 64;
  const int n0 = blockIdx.x * 64;
  const int t  = threadIdx.x;
  {
    const int r  = t >> 2;                 // c row 0..63
    const int cs = (t & 3) * 16;           // n offset
    const float* xp = x + ((size_t)b * CC + c0 + r) * NN + n0 + cs;
    #pragma unroll
    for (int i = 0; i < 4; ++i) {
      float4 v = *(const float4*)(xp + i * 4);
      *(float4*)&tile[r][cs + i * 4] = v;
    }
  }
  __syncthreads();
  const int nl = t >> 2;                   // n row 0..63
  const int cl = (t & 3) * 16;             // c offset
  union { ushort s[16]; uint4 q[2]; } pk;
  #pragma unroll
  for (int i = 0; i < 16; ++i) pk.s[i] = f2bf(tile[cl + i][nl]);
  uint4* dst = (uint4*)(xT + ((size_t)b * NN + n0 + nl) * CC + c0 + cl);
  dst[0] = pk.q[0];
  dst[1] = pk.q[1];
}

// K1: hT[b][n][c] = (1+eps)*xT[b][n][c] + sum_k xT[b][idx[b,n,k]][c]   (bf16)
__global__ __launch_bounds__(256) void k_gather(
    const ushort* __restrict__ xT, const int* __restrict__ edge0,
    const float* __restrict__ eps, ushort* __restrict__ hT)
{
  const int b    = blockIdx.y;
  const int n0   = blockIdx.x * 16;
  const int t    = threadIdx.x;
  const int wave = t >> 6, lane = t & 63;
  const float epsv = 1.0f + eps[0];
  const int c4 = lane * 4;                 // 4 channels per lane
  const ushort* xb = xT + (size_t)b * NN * CC;
  for (int i = 0; i < 4; ++i) {
    const int n = n0 + wave * 4 + i;
    ushort4 sv = *(const ushort4*)(xb + (size_t)n * CC + c4);
    float a0 = bf2f(sv.x) * epsv;
    float a1 = bf2f(sv.y) * epsv;
    float a2 = bf2f(sv.z) * epsv;
    float a3 = bf2f(sv.w) * epsv;
    const int* ep = edge0 + ((size_t)b * NN + n) * KK;
    #pragma unroll
    for (int k = 0; k < KK; ++k) {
      const int j = ep[k];
      ushort4 g = *(const ushort4*)(xb + (size_t)j * CC + c4);
      a0 += bf2f(g.x); a1 += bf2f(g.y); a2 += bf2f(g.z); a3 += bf2f(g.w);
    }
    ushort4 o;
    o.x = f2bf(a0); o.y = f2bf(a1); o.z = f2bf(a2); o.w = f2bf(a3);
    *(ushort4*)(hT + ((size_t)b * NN + n) * CC + c4) = o;
  }
}

// K2: out[b][o][n] = relu( sum_c W[o][c]*hT[b][n][c] + bias[o] )  via MFMA
__global__ __launch_bounds__(256) void k_gemm(
    const ushort* __restrict__ hT, const float* __restrict__ W,
    const float* __restrict__ bias, float* __restrict__ out)
{
  __shared__ ushort Wl[64][264];           // row stride 528B = 33*16: aligned, 2-way-max banks
  const int b  = blockIdx.z;
  const int o0 = blockIdx.y * 64;
  const int nb = blockIdx.x * 256;
  const int t  = threadIdx.x;
  const int wave = t >> 6, lane = t & 63;

  {  // stage W[o0..o0+63][:] as bf16 into LDS
    const int r  = t >> 2;
    const int cs = (t & 3) * 64;
    const float* wp = W + (size_t)(o0 + r) * CC + cs;
    #pragma unroll
    for (int i = 0; i < 16; ++i) {
      float4 w4 = *(const float4*)(wp + i * 4);
      ushort4 h4;
      h4.x = f2bf(w4.x); h4.y = f2bf(w4.y); h4.z = f2bf(w4.z); h4.w = f2bf(w4.w);
      *(ushort4*)&Wl[r][cs + i * 4] = h4;
    }
  }
  __syncthreads();

  f32x4 acc[4][4];
  #pragma unroll
  for (int m = 0; m < 4; ++m)
    #pragma unroll
    for (int nn = 0; nn < 4; ++nn) acc[m][nn] = (f32x4){0.f, 0.f, 0.f, 0.f};

  const int lrow = lane & 15;   // M-row for A, N-col for B/D
  const int kgrp = lane >> 4;   // k-group 0..3
  const int nsub = nb + wave * 64;
  const ushort* hb = hT + (size_t)b * NN * CC;

  #pragma unroll
  for (int kc = 0; kc < 8; ++kc) {
    const int c0 = kc * 32;
    bf16x8 afr[4], bfr[4];
    #pragma unroll
    for (int m = 0; m < 4; ++m) {
      const ushort* ap = &Wl[m * 16 + lrow][c0 + kgrp * 8];
      afr[m] = *(const bf16x8*)ap;
    }
    #pragma unroll
    for (int nn = 0; nn < 4; ++nn) {
      const ushort* bp = hb + (size_t)(nsub + nn * 16 + lrow) * CC + c0 + kgrp * 8;
      bfr[nn] = *(const bf16x8*)bp;
    }
    #pragma unroll
    for (int m = 0; m < 4; ++m)
      #pragma unroll
      for (int nn = 0; nn < 4; ++nn)
        acc[m][nn] = __builtin_amdgcn_mfma_f32_16x16x32_bf16(
            afr[m], bfr[nn], acc[m][nn], 0, 0, 0);
  }

  // epilogue: D col = lane&15 (n), row = (lane>>4)*4 + r (o-local); bias + relu
  #pragma unroll
  for (int m = 0; m < 4; ++m) {
    #pragma unroll
    for (int r = 0; r < 4; ++r) {
      const int o  = o0 + m * 16 + kgrp * 4 + r;
      const float bv = bias[o];
      #pragma unroll
      for (int nn = 0; nn < 4; ++nn) {
        const int n = nsub + nn * 16 + lrow;
        float v = acc[m][nn][r] + bv;
        v = v > 0.f ? v : 0.f;
        out[((size_t)b * CC + o) * NN + n] = v;
      }
    }
  }
}

extern "C" void kernel_launch(void* const* d_in, const int* in_sizes, int n_in,
                              void* d_out, int out_size, void* d_ws, size_t ws_size,
                              hipStream_t stream) {
  const float* x    = (const float*)d_in[0];
  const int*   edge = (const int*)d_in[1];   // [2][B][N][K] int32, plane 0 used
  const float* eps  = (const float*)d_in[2];
  const float* W    = (const float*)d_in[3];
  const float* bias = (const float*)d_in[4];
  float* out = (float*)d_out;

  ushort* xT = (ushort*)d_ws;                          // [B][N][C] bf16, 16 MB
  ushort* hT = xT + (size_t)BB * NN * CC;              // [B][N][C] bf16, 16 MB

  dim3 g0(NN / 64, CC / 64, BB);
  k_transpose<<<g0, 256, 0, stream>>>(x, xT);

  dim3 g1(NN / 16, BB);
  k_gather<<<g1, 256, 0, stream>>>(xT, edge, eps, hT);

  dim3 g2(NN / 256, CC / 64, BB);
  k_gemm<<<g2, 256, 0, stream>>>(hT, W, bias, out);
}

// Round 3
// 128.029 us; speedup vs baseline: 1.1322x; 1.1322x over previous
//
#include <hip/hip_runtime.h>
#include <stdint.h>

#define BB 8
#define CC 256
#define NN 4096
#define KK 16
#define NT 32              // n-tile per fused block

typedef float f32x4 __attribute__((ext_vector_type(4)));
typedef short bf16x8 __attribute__((ext_vector_type(8)));

__device__ __forceinline__ ushort f2bf(float f) {
  union { float f; uint32_t u; } v; v.f = f;
  uint32_t r = v.u + 0x7FFFu + ((v.u >> 16) & 1u);   // RNE
  return (ushort)(r >> 16);
}
__device__ __forceinline__ float bf2f(ushort h) {
  union { uint32_t u; float f; } v; v.u = ((uint32_t)h) << 16;
  return v.f;
}

// K0: x[b][c][n] f32 -> xT[b][n][c] bf16  (64x64 LDS tile transpose)
__global__ __launch_bounds__(256) void k_transpose(
    const float* __restrict__ x, ushort* __restrict__ xT)
{
  __shared__ float tile[64][68];
  const int b  = blockIdx.z;
  const int c0 = blockIdx.y * 64;
  const int n0 = blockIdx.x * 64;
  const int t  = threadIdx.x;
  {
    const int r  = t >> 2;
    const int cs = (t & 3) * 16;
    const float* xp = x + ((size_t)b * CC + c0 + r) * NN + n0 + cs;
    #pragma unroll
    for (int i = 0; i < 4; ++i) {
      float4 v = *(const float4*)(xp + i * 4);
      *(float4*)&tile[r][cs + i * 4] = v;
    }
  }
  __syncthreads();
  const int nl = t >> 2;
  const int cl = (t & 3) * 16;
  union { ushort s[16]; uint4 q[2]; } pk;
  #pragma unroll
  for (int i = 0; i < 16; ++i) pk.s[i] = f2bf(tile[cl + i][nl]);
  uint4* dst = (uint4*)(xT + ((size_t)b * NN + n0 + nl) * CC + c0 + cl);
  dst[0] = pk.q[0];
  dst[1] = pk.q[1];
}

// K1: W[o][c] f32 -> Wfrag[kc][o][ks] bf16  (fragment-major: kc=c/32, ks=c%32)
__global__ __launch_bounds__(256) void k_wconv(
    const float* __restrict__ W, ushort* __restrict__ Wfrag)
{
  const int t  = threadIdx.x;
  const int o  = blockIdx.x * 4 + (t >> 6);
  const int k0 = (t & 63) * 4;
  float4 v = *(const float4*)(W + (size_t)o * CC + k0);
  ushort4 h;
  h.x = f2bf(v.x); h.y = f2bf(v.y); h.z = f2bf(v.z); h.w = f2bf(v.w);
  const int kc = k0 >> 5, ks = k0 & 31;
  *(ushort4*)(Wfrag + ((size_t)(kc * CC + o)) * 32 + ks) = h;
}

// K2 fused: gather+GIN update into LDS tile, then MFMA GEMM + bias + ReLU.
// blockIdx.x = tile*8 + b  (b = bid&7 -> XCD i%8 owns exactly one batch slab)
__global__ __launch_bounds__(256) void k_fused(
    const ushort* __restrict__ xT, const int* __restrict__ edge0,
    const float* __restrict__ eps, const ushort* __restrict__ Wfrag,
    const float* __restrict__ bias, float* __restrict__ out)
{
  __shared__ ushort hLds[NT][264];         // 528B row stride: conflict-free b128
  const int bid = blockIdx.x;
  const int b   = bid & 7;
  const int n0  = (bid >> 3) * NT;
  const int t    = threadIdx.x;
  const int wave = t >> 6, lane = t & 63;
  const float epsv = 1.0f + eps[0];
  const ushort* xb = xT + (size_t)b * NN * CC;
  const int c4 = lane * 4;                 // 4 channels per lane

  // Phase 1: gather + GIN update -> hLds
  for (int i = 0; i < NT / 4; ++i) {
    const int nl = wave * (NT / 4) + i;
    const int n  = n0 + nl;
    ushort4 sv = *(const ushort4*)(xb + (size_t)n * CC + c4);
    float a0 = bf2f(sv.x) * epsv;
    float a1 = bf2f(sv.y) * epsv;
    float a2 = bf2f(sv.z) * epsv;
    float a3 = bf2f(sv.w) * epsv;
    const int4* epv = (const int4*)(edge0 + ((size_t)b * NN + n) * KK);
    int4 e0 = epv[0], e1 = epv[1], e2 = epv[2], e3 = epv[3];
    const int js[16] = {e0.x, e0.y, e0.z, e0.w, e1.x, e1.y, e1.z, e1.w,
                        e2.x, e2.y, e2.z, e2.w, e3.x, e3.y, e3.z, e3.w};
    #pragma unroll
    for (int k = 0; k < KK; ++k) {
      ushort4 g = *(const ushort4*)(xb + (size_t)js[k] * CC + c4);
      a0 += bf2f(g.x); a1 += bf2f(g.y); a2 += bf2f(g.z); a3 += bf2f(g.w);
    }
    ushort4 o4;
    o4.x = f2bf(a0); o4.y = f2bf(a1); o4.z = f2bf(a2); o4.w = f2bf(a3);
    *(ushort4*)&hLds[nl][c4] = o4;
  }
  __syncthreads();

  // Phase 2: GEMM. Wave w computes o in [w*64, w*64+64) x all NT n.
  f32x4 acc[4][NT / 16];
  #pragma unroll
  for (int m = 0; m < 4; ++m)
    #pragma unroll
    for (int nn = 0; nn < NT / 16; ++nn) acc[m][nn] = (f32x4){0.f, 0.f, 0.f, 0.f};

  const int lrow = lane & 15;
  const int kgrp = lane >> 4;
  const int o0   = wave * 64;

  #pragma unroll
  for (int kc = 0; kc < 8; ++kc) {
    const int cs = kgrp * 8;
    bf16x8 afr[4], bfr[NT / 16];
    #pragma unroll
    for (int m = 0; m < 4; ++m)
      afr[m] = *(const bf16x8*)(Wfrag +
          ((size_t)(kc * CC + o0 + m * 16 + lrow)) * 32 + cs);
    #pragma unroll
    for (int nn = 0; nn < NT / 16; ++nn)
      bfr[nn] = *(const bf16x8*)&hLds[nn * 16 + lrow][kc * 32 + cs];
    #pragma unroll
    for (int m = 0; m < 4; ++m)
      #pragma unroll
      for (int nn = 0; nn < NT / 16; ++nn)
        acc[m][nn] = __builtin_amdgcn_mfma_f32_16x16x32_bf16(
            afr[m], bfr[nn], acc[m][nn], 0, 0, 0);
  }

  // Epilogue: D col=lane&15 (n), row=(lane>>4)*4+r (o-local); bias + relu
  #pragma unroll
  for (int m = 0; m < 4; ++m) {
    #pragma unroll
    for (int r = 0; r < 4; ++r) {
      const int o  = o0 + m * 16 + kgrp * 4 + r;
      const float bv = bias[o];
      #pragma unroll
      for (int nn = 0; nn < NT / 16; ++nn) {
        const int n = n0 + nn * 16 + lrow;
        float v = acc[m][nn][r] + bv;
        v = v > 0.f ? v : 0.f;
        out[((size_t)b * CC + o) * NN + n] = v;
      }
    }
  }
}

extern "C" void kernel_launch(void* const* d_in, const int* in_sizes, int n_in,
                              void* d_out, int out_size, void* d_ws, size_t ws_size,
                              hipStream_t stream) {
  const float* x    = (const float*)d_in[0];
  const int*   edge = (const int*)d_in[1];   // [2][B][N][K] int32, plane 0 used
  const float* eps  = (const float*)d_in[2];
  const float* W    = (const float*)d_in[3];
  const float* bias = (const float*)d_in[4];
  float* out = (float*)d_out;

  ushort* xT    = (ushort*)d_ws;                         // [B][N][C] bf16, 16.8 MB
  ushort* Wfrag = xT + (size_t)BB * NN * CC;             // [8][C][32] bf16, 128 KB

  dim3 g0(NN / 64, CC / 64, BB);
  k_transpose<<<g0, 256, 0, stream>>>(x, xT);

  k_wconv<<<CC / 4, 256, 0, stream>>>(W, Wfrag);

  k_fused<<<BB * (NN / NT), 256, 0, stream>>>(xT, edge, eps, Wfrag, bias, out);
}

// Round 5
// 121.087 us; speedup vs baseline: 1.1971x; 1.0573x over previous
//
#include <hip/hip_runtime.h>
#include <stdint.h>

#define BB 8
#define CC 256
#define NN 4096
#define KK 16
#define NT 32              // n-tile per fused block

typedef float f32x4 __attribute__((ext_vector_type(4)));
typedef short bf16x8 __attribute__((ext_vector_type(8)));
typedef int   i32x4 __attribute__((ext_vector_type(4)));

__device__ __forceinline__ ushort f2bf(float f) {
  union { float f; uint32_t u; } v; v.f = f;
  uint32_t r = v.u + 0x7FFFu + ((v.u >> 16) & 1u);   // RNE
  return (ushort)(r >> 16);
}
__device__ __forceinline__ float bf2f(ushort h) {
  union { uint32_t u; float f; } v; v.u = ((uint32_t)h) << 16;
  return v.f;
}

// K0 combined prep:
//  blocks [0,2048): x[b][c][n] f32 -> xT[b][n][c] bf16, with b = bid&7 so
//                   batch b's xT slab is produced on XCD b (L2-resident for K1).
//  blocks [2048,2112): W[o][c] f32 -> Wfrag[kc][o][ks] bf16 (kc=c/32, ks=c%32)
__global__ __launch_bounds__(256) void k_prep(
    const float* __restrict__ x, const float* __restrict__ W,
    ushort* __restrict__ xT, ushort* __restrict__ Wfrag)
{
  const int bid = blockIdx.x;
  const int t   = threadIdx.x;
  if (bid >= 2048) {                       // W conversion
    const int wb = bid - 2048;
    const int o  = wb * 4 + (t >> 6);
    const int k0 = (t & 63) * 4;
    float4 v = *(const float4*)(W + (size_t)o * CC + k0);
    ushort4 h;
    h.x = f2bf(v.x); h.y = f2bf(v.y); h.z = f2bf(v.z); h.w = f2bf(v.w);
    const int kc = k0 >> 5, ks = k0 & 31;
    *(ushort4*)(Wfrag + ((size_t)(kc * CC + o)) * 32 + ks) = h;
    return;
  }
  __shared__ float tile[64][68];
  const int b    = bid & 7;                // XCD affinity (round-robin i%8)
  const int tl   = bid >> 3;               // 256 tiles per batch
  const int c0   = (tl & 3) * 64;
  const int n0   = (tl >> 2) * 64;
  {
    const int r  = t >> 2;
    const int cs = (t & 3) * 16;
    const float* xp = x + ((size_t)b * CC + c0 + r) * NN + n0 + cs;
    #pragma unroll
    for (int i = 0; i < 4; ++i) {
      float4 v = *(const float4*)(xp + i * 4);
      *(float4*)&tile[r][cs + i * 4] = v;
    }
  }
  __syncthreads();
  const int nl = t >> 2;
  const int cl = (t & 3) * 16;
  union { ushort s[16]; uint4 q[2]; } pk;
  #pragma unroll
  for (int i = 0; i < 16; ++i) pk.s[i] = f2bf(tile[cl + i][nl]);
  uint4* dst = (uint4*)(xT + ((size_t)b * NN + n0 + nl) * CC + c0 + cl);
  dst[0] = pk.q[0];
  dst[1] = pk.q[1];
}

// K1 fused: gather+GIN update into LDS tile, then MFMA GEMM + bias + ReLU.
// blockIdx.x = tile*8 + b  (b = bid&7 -> same XCD that produced batch b's xT)
__global__ __launch_bounds__(256) void k_fused(
    const ushort* __restrict__ xT, const int* __restrict__ edge0,
    const float* __restrict__ eps, const ushort* __restrict__ Wfrag,
    const float* __restrict__ bias, float* __restrict__ out)
{
  __shared__ ushort hLds[NT][264];         // 528B row stride
  const int bid = blockIdx.x;
  const int b   = bid & 7;
  const int n0  = (bid >> 3) * NT;
  const int t    = threadIdx.x;
  const int wave = t >> 6, lane = t & 63;
  const float epsv = 1.0f + eps[0];
  const ushort* xb = xT + (size_t)b * NN * CC;

  // Phase 1: gather + GIN update -> hLds.
  // Lane halves split two n-rows: each lane owns 8 channels -> bf16x8 (16B)
  // loads, 1KB/wave per gather instruction.
  const int half = lane >> 5;
  const int cl   = (lane & 31) * 8;
  #pragma unroll
  for (int it = 0; it < 4; ++it) {
    const int nl = wave * 8 + it * 2 + half;
    const int n  = n0 + nl;
    bf16x8 sv = *(const bf16x8*)(xb + (size_t)n * CC + cl);
    float a[8];
    #pragma unroll
    for (int j = 0; j < 8; ++j) a[j] = bf2f((ushort)sv[j]) * epsv;
    const i32x4* epv = (const i32x4*)(edge0 + ((size_t)b * NN + n) * KK);
    i32x4 e0 = __builtin_nontemporal_load(epv + 0);
    i32x4 e1 = __builtin_nontemporal_load(epv + 1);
    i32x4 e2 = __builtin_nontemporal_load(epv + 2);
    i32x4 e3 = __builtin_nontemporal_load(epv + 3);
    const int js[16] = {e0.x, e0.y, e0.z, e0.w, e1.x, e1.y, e1.z, e1.w,
                        e2.x, e2.y, e2.z, e2.w, e3.x, e3.y, e3.z, e3.w};
    #pragma unroll
    for (int k = 0; k < KK; ++k) {
      bf16x8 g = *(const bf16x8*)(xb + (size_t)js[k] * CC + cl);
      #pragma unroll
      for (int j = 0; j < 8; ++j) a[j] += bf2f((ushort)g[j]);
    }
    union { ushort s[8]; bf16x8 v; } pk;
    #pragma unroll
    for (int j = 0; j < 8; ++j) pk.s[j] = f2bf(a[j]);
    *(bf16x8*)&hLds[nl][cl] = pk.v;
  }
  __syncthreads();

  // Phase 2: GEMM. Wave w computes o in [w*64, w*64+64) x all NT n.
  f32x4 acc[4][NT / 16];
  #pragma unroll
  for (int m = 0; m < 4; ++m)
    #pragma unroll
    for (int nn = 0; nn < NT / 16; ++nn) acc[m][nn] = (f32x4){0.f, 0.f, 0.f, 0.f};

  const int lrow = lane & 15;
  const int kgrp = lane >> 4;
  const int o0   = wave * 64;

  #pragma unroll
  for (int kc = 0; kc < 8; ++kc) {
    const int cs = kgrp * 8;
    bf16x8 afr[4], bfr[NT / 16];
    #pragma unroll
    for (int m = 0; m < 4; ++m)
      afr[m] = *(const bf16x8*)(Wfrag +
          ((size_t)(kc * CC + o0 + m * 16 + lrow)) * 32 + cs);
    #pragma unroll
    for (int nn = 0; nn < NT / 16; ++nn)
      bfr[nn] = *(const bf16x8*)&hLds[nn * 16 + lrow][kc * 32 + cs];
    #pragma unroll
    for (int m = 0; m < 4; ++m)
      #pragma unroll
      for (int nn = 0; nn < NT / 16; ++nn)
        acc[m][nn] = __builtin_amdgcn_mfma_f32_16x16x32_bf16(
            afr[m], bfr[nn], acc[m][nn], 0, 0, 0);
  }

  // Epilogue: D col=lane&15 (n), row=(lane>>4)*4+r (o-local); bias + relu.
  // Nontemporal: out is touch-once, keep L2 for xT gathers of other blocks.
  #pragma unroll
  for (int m = 0; m < 4; ++m) {
    #pragma unroll
    for (int r = 0; r < 4; ++r) {
      const int o  = o0 + m * 16 + kgrp * 4 + r;
      const float bv = bias[o];
      #pragma unroll
      for (int nn = 0; nn < NT / 16; ++nn) {
        const int n = n0 + nn * 16 + lrow;
        float v = acc[m][nn][r] + bv;
        v = v > 0.f ? v : 0.f;
        __builtin_nontemporal_store(v, &out[((size_t)b * CC + o) * NN + n]);
      }
    }
  }
}

extern "C" void kernel_launch(void* const* d_in, const int* in_sizes, int n_in,
                              void* d_out, int out_size, void* d_ws, size_t ws_size,
                              hipStream_t stream) {
  const float* x    = (const float*)d_in[0];
  const int*   edge = (const int*)d_in[1];   // [2][B][N][K] int32, plane 0 used
  const float* eps  = (const float*)d_in[2];
  const float* W    = (const float*)d_in[3];
  const float* bias = (const float*)d_in[4];
  float* out = (float*)d_out;

  ushort* xT    = (ushort*)d_ws;                         // [B][N][C] bf16, 16.8 MB
  ushort* Wfrag = xT + (size_t)BB * NN * CC;             // [8][C][32] bf16, 128 KB

  k_prep<<<2048 + 64, 256, 0, stream>>>(x, W, xT, Wfrag);

  k_fused<<<BB * (NN / NT), 256, 0, stream>>>(xT, edge, eps, Wfrag, bias, out);
}